// Round 10
// baseline (95.818 us; speedup 1.0000x reference)
//
#include <hip/hip_runtime.h>
#include <math.h>

#define Bq 4
#define Kq 16
#define Nq 2048
#define Dq 256
#define MAGIC 0x4D414731u

typedef float f32x4 __attribute__((ext_vector_type(4)));
typedef short s16x8 __attribute__((ext_vector_type(8)));
typedef unsigned int u32;

union frag_u { s16x8 v; u32 w[4]; };

// ws layout (floats):
//   [0    .. 1024)  : S1  lane layout [b][lane] (f32x4)
//   [1024 .. 2048)  : G_I lane layout [b][lane] (f32x4)
//   [2048 .. 10240) : logits (4 x 2048)
//   [10240..10244)  : 4 u32 publish flags (== MAGIC when S1/G_I[b] valid)

static __device__ __forceinline__ u32 cvtpk(float a, float b) {
    u32 r;
    asm("v_cvt_pk_bf16_f32 %0, %1, %2" : "=v"(r) : "v"(a), "v"(b));
    return r;
}

static __device__ __forceinline__ void cvt2(float a, float b, u32* hw, u32* lw) {
    const u32 h = cvtpk(a, b);
    const float h0 = __uint_as_float(h << 16);
    const float h1 = __uint_as_float(h & 0xFFFF0000u);
    *hw = h;
    *lw = cvtpk(a - h0, b - h1);
}

static __device__ __forceinline__ void conv8(const f32x4 a, const f32x4 b,
                                             s16x8* hi, s16x8* lo) {
    frag_u H, L;
    cvt2(a[0], a[1], &H.w[0], &L.w[0]);
    cvt2(a[2], a[3], &H.w[1], &L.w[1]);
    cvt2(b[0], b[1], &H.w[2], &L.w[2]);
    cvt2(b[2], b[3], &H.w[3], &L.w[3]);
    *hi = H.v; *lo = L.v;
}

static __device__ __forceinline__ float rdlane(float x, int l) {
    return __uint_as_float((u32)__builtin_amdgcn_readlane((int)__float_as_uint(x), l));
}

#define MFMA(A, B, C) __builtin_amdgcn_mfma_f32_16x16x32_bf16((A), (B), (C), 0, 0, 0)

// partial Gram over one 64-wide K slice (4 f32x4 per lane = 2 MFMA k-windows)
static __device__ __forceinline__ f32x4 gram2(const f32x4* x, f32x4 g) {
    s16x8 hi, lo;
    conv8(x[0], x[1], &hi, &lo);
    g = MFMA(hi, hi, g); g = MFMA(hi, lo, g); g = MFMA(lo, hi, g);
    conv8(x[2], x[3], &hi, &lo);
    g = MFMA(hi, hi, g); g = MFMA(hi, lo, g); g = MFMA(lo, hi, g);
    return g;
}

// (G + lam I) M = (rho-1) G - lam I solved per-wave: lane j (mod 16) owns
// column j; pivot broadcast via v_readlane (static index). Returns S = M*M
// in MFMA C/D lane layout. scr = per-block [16][20] LDS scratch (wave-local).
static __device__ __forceinline__ f32x4 solve_S(f32x4 g, float lam, float rho,
                                                float (*scr)[20], int lane) {
    const int ccol = lane & 15, kgrp = lane >> 4, arow = ccol, j = ccol;
    *reinterpret_cast<f32x4*>(&scr[ccol][kgrp * 4]) = g;
    __builtin_amdgcn_wave_barrier();
    float A[16], rhs[16];
    {
        const float* col = &scr[j][0];
        const f32x4 c0 = *reinterpret_cast<const f32x4*>(col + 0);
        const f32x4 c1 = *reinterpret_cast<const f32x4*>(col + 4);
        const f32x4 c2 = *reinterpret_cast<const f32x4*>(col + 8);
        const f32x4 c3 = *reinterpret_cast<const f32x4*>(col + 12);
        float gv[16];
#pragma unroll
        for (int q = 0; q < 4; ++q) {
            gv[q] = c0[q]; gv[4 + q] = c1[q]; gv[8 + q] = c2[q]; gv[12 + q] = c3[q];
        }
#pragma unroll
        for (int i = 0; i < 16; ++i) {
            const float dv = (i == j) ? lam : 0.f;
            A[i]   = gv[i] + dv;
            rhs[i] = (rho - 1.f) * gv[i] - dv;
        }
    }
    __builtin_amdgcn_wave_barrier();

#pragma unroll
    for (int k = 0; k < Kq; ++k) {
        const float pinv = 1.0f / rdlane(A[k], k);
        A[k]   *= pinv;
        rhs[k] *= pinv;
#pragma unroll
        for (int i = 0; i < 16; ++i) {
            if (i == k) continue;
            const float fac = rdlane(A[i], k);
            A[i]   = fmaf(-fac, A[k],   A[i]);
            rhs[i] = fmaf(-fac, rhs[k], rhs[i]);
        }
    }
#pragma unroll
    for (int i = 0; i < 16; ++i) scr[i][j] = rhs[i];
    __builtin_amdgcn_wave_barrier();

    frag_u H, L;
#pragma unroll
    for (int e = 0; e < 8; e += 2) {
        const int kk = (kgrp & 1) * 8 + e;
        const bool vld = (lane < 32);
        const float m0 = vld ? scr[arow][kk]     : 0.f;
        const float m1 = vld ? scr[arow][kk + 1] : 0.f;
        cvt2(m0, m1, &H.w[e >> 1], &L.w[e >> 1]);
    }
    f32x4 s = {0.f, 0.f, 0.f, 0.f};
    s = MFMA(H.v, H.v, s); s = MFMA(H.v, L.v, s); s = MFMA(L.v, H.v, s);
    return s;
}

// ONE main kernel: 2048 blocks x 256 threads, text n = blockIdx.x.
// All blocks: cooperative text Gram (wave w does K-slice w), wave 0 solves.
// Blocks 0-3 additionally compute img matrix n the same cooperative way,
// publish S1/G_I to ws with release-MAGIC flags; consumers acquire-spin only
// AFTER their own text solve (expected spin ~ 0).
__global__ __launch_bounds__(256) void main_kernel(const float* __restrict__ img,
                                                   const float* __restrict__ text,
                                                   const float* __restrict__ r,
                                                   const float* __restrict__ alp,
                                                   const float* __restrict__ scale,
                                                   float* __restrict__ ws) {
    __shared__ __align__(16) f32x4 shG[4][64];
    __shared__ __align__(16) f32x4 shGim[4][64];
    __shared__ __align__(16) float scr[16][20];
    const int tid  = threadIdx.x;
    const int w    = tid >> 6, lane = tid & 63;
    const int arow = lane & 15, kgrp = lane >> 4;
    const int n    = blockIdx.x;
    const bool isProd = (n < 4);

    // text K-slice loads (4 f32x4/lane) + img K-slice for producer blocks
    const float* baseT = text + n * (Kq * Dq) + arow * Dq + kgrp * 8;
    f32x4 xt[4];
    xt[0] = *reinterpret_cast<const f32x4*>(baseT + (2 * w) * 32);
    xt[1] = *reinterpret_cast<const f32x4*>(baseT + (2 * w) * 32 + 4);
    xt[2] = *reinterpret_cast<const f32x4*>(baseT + (2 * w + 1) * 32);
    xt[3] = *reinterpret_cast<const f32x4*>(baseT + (2 * w + 1) * 32 + 4);

    if (isProd) {
        const float* baseI = img + n * (Kq * Dq) + arow * Dq + kgrp * 8;
        f32x4 xi[4];
        xi[0] = *reinterpret_cast<const f32x4*>(baseI + (2 * w) * 32);
        xi[1] = *reinterpret_cast<const f32x4*>(baseI + (2 * w) * 32 + 4);
        xi[2] = *reinterpret_cast<const f32x4*>(baseI + (2 * w + 1) * 32);
        xi[3] = *reinterpret_cast<const f32x4*>(baseI + (2 * w + 1) * 32 + 4);
        f32x4 gi = {0.f, 0.f, 0.f, 0.f};
        shGim[w][lane] = gram2(xi, gi);
    }
    f32x4 g = {0.f, 0.f, 0.f, 0.f};
    shG[w][lane] = gram2(xt, g);
    __syncthreads();
    if (w != 0) return;   // waves 1-3 done (all reached the barrier)

    u32* flags = reinterpret_cast<u32*>(ws + 10240);

    if (isProd) {
        // img solve FIRST, publish early
        const f32x4 gIm = shGim[0][lane] + shGim[1][lane] + shGim[2][lane] + shGim[3][lane];
        const float lamI = (float(Bq) / float(Dq)) * expf(r[0]) + 1e-6f;
        const float rhoI = expf(r[1]);
        const f32x4 sI = solve_S(gIm, lamI, rhoI, scr, lane);
        reinterpret_cast<f32x4*>(ws)[n * 64 + lane]        = sI;
        reinterpret_cast<f32x4*>(ws + 1024)[n * 64 + lane] = gIm;
        __threadfence();
        if (lane == 0)
            __hip_atomic_store(&flags[n], MAGIC, __ATOMIC_RELEASE, __HIP_MEMORY_SCOPE_AGENT);
    }

    const f32x4 gT = shG[0][lane] + shG[1][lane] + shG[2][lane] + shG[3][lane];
    const float lamT = (float(Nq) / float(Dq)) * expf(r[2]) + 1e-6f;
    const float rhoT = expf(r[3]);
    const f32x4 sT = solve_S(gT, lamT, rhoT, scr, lane);

    // acquire all 4 published img results (usually already set)
#pragma unroll
    for (int i = 0; i < 4; ++i) {
        while (__hip_atomic_load(&flags[i], __ATOMIC_ACQUIRE, __HIP_MEMORY_SCOPE_AGENT) != MAGIC)
            __builtin_amdgcn_s_sleep(2);
    }

    f32x4 s1v[4], giv[4];
#pragma unroll
    for (int b = 0; b < 4; ++b) {
        s1v[b] = reinterpret_cast<const f32x4*>(ws)[b * 64 + lane];
        giv[b] = reinterpret_cast<const f32x4*>(ws + 1024)[b * 64 + lane];
    }
    float p[8];
#pragma unroll
    for (int b = 0; b < 4; ++b) {
        p[b]     = s1v[b][0] * gT[0] + s1v[b][1] * gT[1] + s1v[b][2] * gT[2] + s1v[b][3] * gT[3];
        p[4 + b] = giv[b][0] * sT[0] + giv[b][1] * sT[1] + giv[b][2] * sT[2] + giv[b][3] * sT[3];
    }
#pragma unroll
    for (int off = 32; off; off >>= 1) {
#pragma unroll
        for (int q = 0; q < 8; ++q) p[q] += __shfl_down(p[q], off, 64);
    }
    if (lane == 0) {
        const float a = alp[0], sc = scale[0];
        float* logits = ws + 2048;
#pragma unroll
        for (int b = 0; b < 4; ++b) {
            const float d1 = -p[b] * (1.f / Kq);
            const float d2 = -p[4 + b] * (1.f / Kq);
            logits[b * Nq + n] = sc * (a * d1 + (1.f - a) * d2);
        }
    }
}

__global__ __launch_bounds__(256) void softmax_kernel(const float* __restrict__ logits,
                                                      const float* __restrict__ lsc,
                                                      float* __restrict__ out) {
    const int b   = blockIdx.x;
    const int tid = threadIdx.x;
    const float* row = logits + b * Nq;
    __shared__ float sh[4];
    float v[8];
    float mx = -INFINITY;
#pragma unroll
    for (int q = 0; q < 8; ++q) {
        v[q] = row[tid + q * 256];
        mx = fmaxf(mx, v[q]);
    }
#pragma unroll
    for (int off = 32; off; off >>= 1) mx = fmaxf(mx, __shfl_down(mx, off, 64));
    if ((tid & 63) == 0) sh[tid >> 6] = mx;
    __syncthreads();
    mx = fmaxf(fmaxf(sh[0], sh[1]), fmaxf(sh[2], sh[3]));

    float sum = 0.f;
#pragma unroll
    for (int q = 0; q < 8; ++q) sum += expf(v[q] - mx);
#pragma unroll
    for (int off = 32; off; off >>= 1) sum += __shfl_down(sum, off, 64);
    __syncthreads();
    if ((tid & 63) == 0) sh[tid >> 6] = sum;
    __syncthreads();
    sum = sh[0] + sh[1] + sh[2] + sh[3];

    const float lse = mx + logf(sum);
#pragma unroll
    for (int q = 0; q < 8; ++q) out[b * Nq + tid + q * 256] = v[q] - lse;
    if (b == 0 && tid == 0) out[Bq * Nq] = 1.f / (1.f + expf(-lsc[0]));
}

extern "C" void kernel_launch(void* const* d_in, const int* in_sizes, int n_in,
                              void* d_out, int out_size, void* d_ws, size_t ws_size,
                              hipStream_t stream) {
    const float* img   = (const float*)d_in[0];
    const float* text  = (const float*)d_in[1];
    const float* r     = (const float*)d_in[2];
    const float* alp   = (const float*)d_in[3];
    const float* scale = (const float*)d_in[4];
    const float* lsc   = (const float*)d_in[5];
    float* ws  = (float*)d_ws;
    float* out = (float*)d_out;

    // invalidate flags from the previous call so this call's publish is fresh
    hipMemsetAsync(ws + 10240, 0, 4 * sizeof(u32), stream);
    main_kernel<<<Nq, 256, 0, stream>>>(img, text, r, alp, scale, ws);
    softmax_kernel<<<Bq, 256, 0, stream>>>(ws + 2048, lsc, out);
}

// Round 11
// 28.726 us; speedup vs baseline: 3.3355x; 3.3355x over previous
//
#include <hip/hip_runtime.h>
#include <math.h>

#define Bq 4
#define Kq 16
#define Nq 2048
#define Dq 256

typedef float f32x4 __attribute__((ext_vector_type(4)));
typedef short s16x8 __attribute__((ext_vector_type(8)));
typedef unsigned int u32;

union frag_u { s16x8 v; u32 w[4]; };

// ws layout (floats):
//   [0    .. 1024)  : S1  lane layout [b][lane] (f32x4)
//   [1024 .. 2048)  : G_I lane layout [b][lane] (f32x4)
//   [2048 .. 10240) : logits (4 x 2048)

static __device__ __forceinline__ u32 cvtpk(float a, float b) {
    u32 r;
    asm("v_cvt_pk_bf16_f32 %0, %1, %2" : "=v"(r) : "v"(a), "v"(b));
    return r;
}

static __device__ __forceinline__ void cvt2(float a, float b, u32* hw, u32* lw) {
    const u32 h = cvtpk(a, b);
    const float h0 = __uint_as_float(h << 16);
    const float h1 = __uint_as_float(h & 0xFFFF0000u);
    *hw = h;
    *lw = cvtpk(a - h0, b - h1);
}

static __device__ __forceinline__ void conv8(const f32x4 a, const f32x4 b,
                                             s16x8* hi, s16x8* lo) {
    frag_u H, L;
    cvt2(a[0], a[1], &H.w[0], &L.w[0]);
    cvt2(a[2], a[3], &H.w[1], &L.w[1]);
    cvt2(b[0], b[1], &H.w[2], &L.w[2]);
    cvt2(b[2], b[3], &H.w[3], &L.w[3]);
    *hi = H.v; *lo = L.v;
}

#define MFMA(A, B, C) __builtin_amdgcn_mfma_f32_16x16x32_bf16((A), (B), (C), 0, 0, 0)

// partial Gram over one 64-wide K slice (4 f32x4 per lane = 2 MFMA k-windows)
static __device__ __forceinline__ f32x4 gram2(const f32x4* x, f32x4 g) {
    s16x8 hi, lo;
    conv8(x[0], x[1], &hi, &lo);
    g = MFMA(hi, hi, g); g = MFMA(hi, lo, g); g = MFMA(lo, hi, g);
    conv8(x[2], x[3], &hi, &lo);
    g = MFMA(hi, hi, g); g = MFMA(hi, lo, g); g = MFMA(lo, hi, g);
    return g;
}

// Wave-synchronous LDS Gauss-Jordan (LOOPED, compact code): solves
// (G + lam I) M = (rho-1) G - lam I, returns S = M*M in MFMA C/D lane layout.
// Aug = per-wave [16][34] LDS, interleaved [row][2*col+{A,RHS}].
static __device__ __forceinline__ f32x4 solve_S_lds(f32x4 g, float lam, float rho,
                                                    float (*Aug)[34], int lane) {
    const int ccol = lane & 15, kgrp = lane >> 4, arow = ccol;
#pragma unroll
    for (int q = 0; q < 4; ++q) {
        const int rr = kgrp * 4 + q;
        const float dv = (rr == ccol) ? lam : 0.f;
        float2 pr; pr.x = g[q] + dv; pr.y = (rho - 1.f) * g[q] - dv;
        *reinterpret_cast<float2*>(&Aug[rr][2 * ccol]) = pr;
    }
    __builtin_amdgcn_wave_barrier();

#pragma unroll 1
    for (int k = 0; k < Kq; ++k) {
        const float2 pv = *reinterpret_cast<const float2*>(&Aug[k][2 * k]);
        const float pinv = 1.f / pv.x;
        const float2 pk = *reinterpret_cast<const float2*>(&Aug[k][2 * ccol]);
        float fac[4];
#pragma unroll
        for (int q = 0; q < 4; ++q) fac[q] = Aug[kgrp * 4 + q][2 * k];
        __builtin_amdgcn_wave_barrier();
#pragma unroll
        for (int q = 0; q < 4; ++q) {
            const int rr = kgrp * 4 + q;
            float2 cur = *reinterpret_cast<const float2*>(&Aug[rr][2 * ccol]);
            const float f = fac[q] * pinv;
            float2 nw;
            nw.x = (rr == k) ? pk.x * pinv : cur.x - f * pk.x;
            nw.y = (rr == k) ? pk.y * pinv : cur.y - f * pk.y;
            *reinterpret_cast<float2*>(&Aug[rr][2 * ccol]) = nw;
        }
        __builtin_amdgcn_wave_barrier();
    }

    // S = M*M via MFMA (M symmetric, K=16 zero-padded to 32)
    frag_u H, L;
#pragma unroll
    for (int e = 0; e < 8; e += 2) {
        const int kk = (kgrp & 1) * 8 + e;
        const bool vld = (lane < 32);
        const float m0 = vld ? Aug[arow][2 * kk + 1]       : 0.f;
        const float m1 = vld ? Aug[arow][2 * (kk + 1) + 1] : 0.f;
        cvt2(m0, m1, &H.w[e >> 1], &L.w[e >> 1]);
    }
    f32x4 s = {0.f, 0.f, 0.f, 0.f};
    s = MFMA(H.v, H.v, s); s = MFMA(H.v, L.v, s); s = MFMA(L.v, H.v, s);
    return s;
}

// Kernel A: 4 blocks x 64 threads; block b solves img matrix b once.
__global__ __launch_bounds__(64) void img_kernel(const float* __restrict__ img,
                                                 const float* __restrict__ r,
                                                 float* __restrict__ ws) {
    __shared__ __align__(16) float Aug[Kq][34];
    const int lane = threadIdx.x;
    const int b    = blockIdx.x;
    const int arow = lane & 15, kgrp = lane >> 4;

    const float* base = img + b * (Kq * Dq) + arow * Dq + kgrp * 8;
    f32x4 g = {0.f, 0.f, 0.f, 0.f};
#pragma unroll 1
    for (int c = 0; c < 8; c += 2) {
        f32x4 x[4];
        x[0] = *reinterpret_cast<const f32x4*>(base + c * 32);
        x[1] = *reinterpret_cast<const f32x4*>(base + c * 32 + 4);
        x[2] = *reinterpret_cast<const f32x4*>(base + (c + 1) * 32);
        x[3] = *reinterpret_cast<const f32x4*>(base + (c + 1) * 32 + 4);
        g = gram2(x, g);
    }
    const float lam = (float(Bq) / float(Dq)) * expf(r[0]) + 1e-6f;
    const float rho = expf(r[1]);
    const f32x4 s = solve_S_lds(g, lam, rho, Aug, lane);
    reinterpret_cast<f32x4*>(ws)[b * 64 + lane]        = s;
    reinterpret_cast<f32x4*>(ws + 1024)[b * 64 + lane] = g;
}

// Kernel B: 2048 blocks x 256 threads, ONE text per block (all co-resident).
// Wave w: partial Gram over K-slice w; wave 0 reduces + solves (looped
// LDS-GJ, compact code) and writes the 4 logits.
__global__ __launch_bounds__(256) void text_kernel(const float* __restrict__ text,
                                                   const float* __restrict__ r,
                                                   const float* __restrict__ alp,
                                                   const float* __restrict__ scale,
                                                   float* __restrict__ ws) {
    __shared__ __align__(16) f32x4 shG[4][64];
    __shared__ __align__(16) float Aug[Kq][34];
    const int tid  = threadIdx.x;
    const int w    = tid >> 6, lane = tid & 63;
    const int arow = lane & 15, kgrp = lane >> 4;
    const int n    = blockIdx.x;

    const float* base = text + n * (Kq * Dq) + arow * Dq + kgrp * 8;
    f32x4 x[4];
    x[0] = *reinterpret_cast<const f32x4*>(base + (2 * w) * 32);
    x[1] = *reinterpret_cast<const f32x4*>(base + (2 * w) * 32 + 4);
    x[2] = *reinterpret_cast<const f32x4*>(base + (2 * w + 1) * 32);
    x[3] = *reinterpret_cast<const f32x4*>(base + (2 * w + 1) * 32 + 4);

    f32x4 g = {0.f, 0.f, 0.f, 0.f};
    shG[w][lane] = gram2(x, g);
    __syncthreads();
    if (w != 0) return;   // waves 1-3 done (all reached the barrier)

    const f32x4 gT = shG[0][lane] + shG[1][lane] + shG[2][lane] + shG[3][lane];
    const float lamT = (float(Nq) / float(Dq)) * expf(r[2]) + 1e-6f;
    const float rhoT = expf(r[3]);
    const f32x4 sT = solve_S_lds(gT, lamT, rhoT, Aug, lane);

    // img S1/G_I (8KB, L2-hot): load after the solve
    f32x4 s1v[4], giv[4];
#pragma unroll
    for (int b = 0; b < 4; ++b) {
        s1v[b] = reinterpret_cast<const f32x4*>(ws)[b * 64 + lane];
        giv[b] = reinterpret_cast<const f32x4*>(ws + 1024)[b * 64 + lane];
    }
    float p[8];
#pragma unroll
    for (int b = 0; b < 4; ++b) {
        p[b]     = s1v[b][0] * gT[0] + s1v[b][1] * gT[1] + s1v[b][2] * gT[2] + s1v[b][3] * gT[3];
        p[4 + b] = giv[b][0] * sT[0] + giv[b][1] * sT[1] + giv[b][2] * sT[2] + giv[b][3] * sT[3];
    }
#pragma unroll
    for (int off = 32; off; off >>= 1) {
#pragma unroll
        for (int q = 0; q < 8; ++q) p[q] += __shfl_down(p[q], off, 64);
    }
    if (lane == 0) {
        const float a = alp[0], sc = scale[0];
        float* logits = ws + 2048;
#pragma unroll
        for (int b = 0; b < 4; ++b) {
            const float d1 = -p[b] * (1.f / Kq);
            const float d2 = -p[4 + b] * (1.f / Kq);
            logits[b * Nq + n] = sc * (a * d1 + (1.f - a) * d2);
        }
    }
}

__global__ __launch_bounds__(256) void softmax_kernel(const float* __restrict__ logits,
                                                      const float* __restrict__ lsc,
                                                      float* __restrict__ out) {
    const int b   = blockIdx.x;
    const int tid = threadIdx.x;
    const float* row = logits + b * Nq;
    __shared__ float sh[4];
    float v[8];
    float mx = -INFINITY;
#pragma unroll
    for (int q = 0; q < 8; ++q) {
        v[q] = row[tid + q * 256];
        mx = fmaxf(mx, v[q]);
    }
#pragma unroll
    for (int off = 32; off; off >>= 1) mx = fmaxf(mx, __shfl_down(mx, off, 64));
    if ((tid & 63) == 0) sh[tid >> 6] = mx;
    __syncthreads();
    mx = fmaxf(fmaxf(sh[0], sh[1]), fmaxf(sh[2], sh[3]));

    float sum = 0.f;
#pragma unroll
    for (int q = 0; q < 8; ++q) sum += expf(v[q] - mx);
#pragma unroll
    for (int off = 32; off; off >>= 1) sum += __shfl_down(sum, off, 64);
    __syncthreads();
    if ((tid & 63) == 0) sh[tid >> 6] = sum;
    __syncthreads();
    sum = sh[0] + sh[1] + sh[2] + sh[3];

    const float lse = mx + logf(sum);
#pragma unroll
    for (int q = 0; q < 8; ++q) out[b * Nq + tid + q * 256] = v[q] - lse;
    if (b == 0 && tid == 0) out[Bq * Nq] = 1.f / (1.f + expf(-lsc[0]));
}

extern "C" void kernel_launch(void* const* d_in, const int* in_sizes, int n_in,
                              void* d_out, int out_size, void* d_ws, size_t ws_size,
                              hipStream_t stream) {
    const float* img   = (const float*)d_in[0];
    const float* text  = (const float*)d_in[1];
    const float* r     = (const float*)d_in[2];
    const float* alp   = (const float*)d_in[3];
    const float* scale = (const float*)d_in[4];
    const float* lsc   = (const float*)d_in[5];
    float* ws  = (float*)d_ws;
    float* out = (float*)d_out;

    img_kernel<<<Bq, 64, 0, stream>>>(img, r, ws);
    text_kernel<<<Nq, 256, 0, stream>>>(text, r, alp, scale, ws);
    softmax_kernel<<<Bq, 256, 0, stream>>>(ws + 2048, lsc, out);
}

// Round 12
// 22.322 us; speedup vs baseline: 4.2926x; 1.2869x over previous
//
#include <hip/hip_runtime.h>
#include <math.h>

#define Bq 4
#define Kq 16
#define Nq 2048
#define Dq 256

typedef float f32x4 __attribute__((ext_vector_type(4)));
typedef short s16x8 __attribute__((ext_vector_type(8)));
typedef unsigned int u32;

union frag_u { s16x8 v; u32 w[4]; };

// ws layout (floats):
//   [0    .. 1024)  : S1  lane layout [b][lane] (f32x4)
//   [1024 .. 2048)  : G_I lane layout [b][lane] (f32x4)
//   [2048 .. 10240) : logits (4 x 2048)

static __device__ __forceinline__ u32 cvtpk(float a, float b) {
    u32 r;
    asm("v_cvt_pk_bf16_f32 %0, %1, %2" : "=v"(r) : "v"(a), "v"(b));
    return r;
}

static __device__ __forceinline__ void cvt2(float a, float b, u32* hw, u32* lw) {
    const u32 h = cvtpk(a, b);
    const float h0 = __uint_as_float(h << 16);
    const float h1 = __uint_as_float(h & 0xFFFF0000u);
    *hw = h;
    *lw = cvtpk(a - h0, b - h1);
}

static __device__ __forceinline__ void conv8(const f32x4 a, const f32x4 b,
                                             s16x8* hi, s16x8* lo) {
    frag_u H, L;
    cvt2(a[0], a[1], &H.w[0], &L.w[0]);
    cvt2(a[2], a[3], &H.w[1], &L.w[1]);
    cvt2(b[0], b[1], &H.w[2], &L.w[2]);
    cvt2(b[2], b[3], &H.w[3], &L.w[3]);
    *hi = H.v; *lo = L.v;
}

static __device__ __forceinline__ float rdlane(float x, int l) {
    return __uint_as_float((u32)__builtin_amdgcn_readlane((int)__float_as_uint(x), l));
}

#define MFMA(A, B, C) __builtin_amdgcn_mfma_f32_16x16x32_bf16((A), (B), (C), 0, 0, 0)

// partial Gram over one 64-wide K slice (4 f32x4 per lane = 2 MFMA k-windows)
static __device__ __forceinline__ f32x4 gram2(const f32x4* x, f32x4 g) {
    s16x8 hi, lo;
    conv8(x[0], x[1], &hi, &lo);
    g = MFMA(hi, hi, g); g = MFMA(hi, lo, g); g = MFMA(lo, hi, g);
    conv8(x[2], x[3], &hi, &lo);
    g = MFMA(hi, hi, g); g = MFMA(hi, lo, g); g = MFMA(lo, hi, g);
    return g;
}

// (G + lam I) M = (rho-1) G - lam I solved per-wave: lane j (mod 16) owns
// column j; pivot broadcast via v_readlane (static index, fully unrolled).
// Returns S = M*M in MFMA C/D lane layout. scr = per-block [16][20] LDS.
static __device__ __forceinline__ f32x4 solve_S(f32x4 g, float lam, float rho,
                                                float (*scr)[20], int lane) {
    const int ccol = lane & 15, kgrp = lane >> 4, arow = ccol, j = ccol;
    *reinterpret_cast<f32x4*>(&scr[ccol][kgrp * 4]) = g;
    __builtin_amdgcn_wave_barrier();
    float A[16], rhs[16];
    {
        const float* col = &scr[j][0];
        const f32x4 c0 = *reinterpret_cast<const f32x4*>(col + 0);
        const f32x4 c1 = *reinterpret_cast<const f32x4*>(col + 4);
        const f32x4 c2 = *reinterpret_cast<const f32x4*>(col + 8);
        const f32x4 c3 = *reinterpret_cast<const f32x4*>(col + 12);
        float gv[16];
#pragma unroll
        for (int q = 0; q < 4; ++q) {
            gv[q] = c0[q]; gv[4 + q] = c1[q]; gv[8 + q] = c2[q]; gv[12 + q] = c3[q];
        }
#pragma unroll
        for (int i = 0; i < 16; ++i) {
            const float dv = (i == j) ? lam : 0.f;
            A[i]   = gv[i] + dv;
            rhs[i] = (rho - 1.f) * gv[i] - dv;
        }
    }
    __builtin_amdgcn_wave_barrier();

#pragma unroll
    for (int k = 0; k < Kq; ++k) {
        const float pinv = 1.0f / rdlane(A[k], k);
        A[k]   *= pinv;
        rhs[k] *= pinv;
#pragma unroll
        for (int i = 0; i < 16; ++i) {
            if (i == k) continue;
            const float fac = rdlane(A[i], k);
            A[i]   = fmaf(-fac, A[k],   A[i]);
            rhs[i] = fmaf(-fac, rhs[k], rhs[i]);
        }
    }
#pragma unroll
    for (int i = 0; i < 16; ++i) scr[i][j] = rhs[i];
    __builtin_amdgcn_wave_barrier();

    frag_u H, L;
#pragma unroll
    for (int e = 0; e < 8; e += 2) {
        const int kk = (kgrp & 1) * 8 + e;
        const bool vld = (lane < 32);
        const float m0 = vld ? scr[arow][kk]     : 0.f;
        const float m1 = vld ? scr[arow][kk + 1] : 0.f;
        cvt2(m0, m1, &H.w[e >> 1], &L.w[e >> 1]);
    }
    f32x4 s = {0.f, 0.f, 0.f, 0.f};
    s = MFMA(H.v, H.v, s); s = MFMA(H.v, L.v, s); s = MFMA(L.v, H.v, s);
    return s;
}

// Kernel A: 4 blocks x 256 threads (COOPERATIVE, same pattern as text):
// wave w grams K-slice w of img matrix b = blockIdx.x (4 loads/lane, all
// four waves' cold-HBM latencies overlap); wave 0 reduces + solves.
__global__ __launch_bounds__(256) void img_kernel(const float* __restrict__ img,
                                                  const float* __restrict__ r,
                                                  float* __restrict__ ws) {
    __shared__ __align__(16) f32x4 shG[4][64];
    __shared__ __align__(16) float scr[16][20];
    const int tid  = threadIdx.x;
    const int w    = tid >> 6, lane = tid & 63;
    const int arow = lane & 15, kgrp = lane >> 4;
    const int b    = blockIdx.x;

    const float* base = img + b * (Kq * Dq) + arow * Dq + kgrp * 8;
    f32x4 x[4];
    x[0] = *reinterpret_cast<const f32x4*>(base + (2 * w) * 32);
    x[1] = *reinterpret_cast<const f32x4*>(base + (2 * w) * 32 + 4);
    x[2] = *reinterpret_cast<const f32x4*>(base + (2 * w + 1) * 32);
    x[3] = *reinterpret_cast<const f32x4*>(base + (2 * w + 1) * 32 + 4);

    f32x4 g = {0.f, 0.f, 0.f, 0.f};
    shG[w][lane] = gram2(x, g);
    __syncthreads();
    if (w != 0) return;

    const f32x4 gI = shG[0][lane] + shG[1][lane] + shG[2][lane] + shG[3][lane];
    const float lam = (float(Bq) / float(Dq)) * expf(r[0]) + 1e-6f;
    const float rho = expf(r[1]);
    const f32x4 s = solve_S(gI, lam, rho, scr, lane);
    reinterpret_cast<f32x4*>(ws)[b * 64 + lane]        = s;
    reinterpret_cast<f32x4*>(ws + 1024)[b * 64 + lane] = gI;
}

// Kernel B: 2048 blocks x 256 threads, ONE text per block (all co-resident).
// Wave w: partial Gram over K-slice w; wave 0 reduces + solves (register GJ)
// and writes the 4 logits.
__global__ __launch_bounds__(256) void text_kernel(const float* __restrict__ text,
                                                   const float* __restrict__ r,
                                                   const float* __restrict__ alp,
                                                   const float* __restrict__ scale,
                                                   float* __restrict__ ws) {
    __shared__ __align__(16) f32x4 shG[4][64];
    __shared__ __align__(16) float scr[16][20];
    const int tid  = threadIdx.x;
    const int w    = tid >> 6, lane = tid & 63;
    const int arow = lane & 15, kgrp = lane >> 4;
    const int n    = blockIdx.x;

    const float* base = text + n * (Kq * Dq) + arow * Dq + kgrp * 8;
    f32x4 x[4];
    x[0] = *reinterpret_cast<const f32x4*>(base + (2 * w) * 32);
    x[1] = *reinterpret_cast<const f32x4*>(base + (2 * w) * 32 + 4);
    x[2] = *reinterpret_cast<const f32x4*>(base + (2 * w + 1) * 32);
    x[3] = *reinterpret_cast<const f32x4*>(base + (2 * w + 1) * 32 + 4);

    f32x4 g = {0.f, 0.f, 0.f, 0.f};
    shG[w][lane] = gram2(x, g);
    __syncthreads();
    if (w != 0) return;   // waves 1-3 done (all reached the barrier)

    const f32x4 gT = shG[0][lane] + shG[1][lane] + shG[2][lane] + shG[3][lane];
    const float lamT = (float(Nq) / float(Dq)) * expf(r[2]) + 1e-6f;
    const float rhoT = expf(r[3]);
    const f32x4 sT = solve_S(gT, lamT, rhoT, scr, lane);

    // img S1/G_I (8KB, cache-hot): load after the solve
    f32x4 s1v[4], giv[4];
#pragma unroll
    for (int b = 0; b < 4; ++b) {
        s1v[b] = reinterpret_cast<const f32x4*>(ws)[b * 64 + lane];
        giv[b] = reinterpret_cast<const f32x4*>(ws + 1024)[b * 64 + lane];
    }
    float p[8];
#pragma unroll
    for (int b = 0; b < 4; ++b) {
        p[b]     = s1v[b][0] * gT[0] + s1v[b][1] * gT[1] + s1v[b][2] * gT[2] + s1v[b][3] * gT[3];
        p[4 + b] = giv[b][0] * sT[0] + giv[b][1] * sT[1] + giv[b][2] * sT[2] + giv[b][3] * sT[3];
    }
#pragma unroll
    for (int off = 32; off; off >>= 1) {
#pragma unroll
        for (int q = 0; q < 8; ++q) p[q] += __shfl_down(p[q], off, 64);
    }
    if (lane == 0) {
        const float a = alp[0], sc = scale[0];
        float* logits = ws + 2048;
#pragma unroll
        for (int b = 0; b < 4; ++b) {
            const float d1 = -p[b] * (1.f / Kq);
            const float d2 = -p[4 + b] * (1.f / Kq);
            logits[b * Nq + n] = sc * (a * d1 + (1.f - a) * d2);
        }
    }
}

__global__ __launch_bounds__(256) void softmax_kernel(const float* __restrict__ logits,
                                                      const float* __restrict__ lsc,
                                                      float* __restrict__ out) {
    const int b   = blockIdx.x;
    const int tid = threadIdx.x;
    const float* row = logits + b * Nq;
    __shared__ float sh[4];
    float v[8];
    float mx = -INFINITY;
#pragma unroll
    for (int q = 0; q < 8; ++q) {
        v[q] = row[tid + q * 256];
        mx = fmaxf(mx, v[q]);
    }
#pragma unroll
    for (int off = 32; off; off >>= 1) mx = fmaxf(mx, __shfl_down(mx, off, 64));
    if ((tid & 63) == 0) sh[tid >> 6] = mx;
    __syncthreads();
    mx = fmaxf(fmaxf(sh[0], sh[1]), fmaxf(sh[2], sh[3]));

    float sum = 0.f;
#pragma unroll
    for (int q = 0; q < 8; ++q) sum += expf(v[q] - mx);
#pragma unroll
    for (int off = 32; off; off >>= 1) sum += __shfl_down(sum, off, 64);
    __syncthreads();
    if ((tid & 63) == 0) sh[tid >> 6] = sum;
    __syncthreads();
    sum = sh[0] + sh[1] + sh[2] + sh[3];

    const float lse = mx + logf(sum);
#pragma unroll
    for (int q = 0; q < 8; ++q) out[b * Nq + tid + q * 256] = v[q] - lse;
    if (b == 0 && tid == 0) out[Bq * Nq] = 1.f / (1.f + expf(-lsc[0]));
}

extern "C" void kernel_launch(void* const* d_in, const int* in_sizes, int n_in,
                              void* d_out, int out_size, void* d_ws, size_t ws_size,
                              hipStream_t stream) {
    const float* img   = (const float*)d_in[0];
    const float* text  = (const float*)d_in[1];
    const float* r     = (const float*)d_in[2];
    const float* alp   = (const float*)d_in[3];
    const float* scale = (const float*)d_in[4];
    const float* lsc   = (const float*)d_in[5];
    float* ws  = (float*)d_ws;
    float* out = (float*)d_out;

    img_kernel<<<Bq, 256, 0, stream>>>(img, r, ws);
    text_kernel<<<Nq, 256, 0, stream>>>(text, r, alp, scale, ws);
    softmax_kernel<<<Bq, 256, 0, stream>>>(ws + 2048, lsc, out);
}